// Round 11
// baseline (747.495 us; speedup 1.0000x reference)
//
#include <hip/hip_runtime.h>

#define B_SZ 8
#define N_SZ 65536
#define C_SZ 128
#define K_SZ 15
#define THREADS 256
#define ROWS 4                        // c-rows per wave
#define C_BLK 16                      // c-rows per block (4 waves x 4)
#define G 8                           // c-groups (C_SZ / C_BLK)
#define NPL 2                         // n per lane per step
#define WSTEP 128                     // 64 lanes * NPL
#define NSPAN 1024                    // n-span per block
#define S_SPANS 64                    // N_SZ / NSPAN
#define STEPS 8                       // NSPAN / WSTEP
#define PART_PER_BLK (C_BLK * K_SZ)   // 240
#define NBLKS (B_SZ * S_SPANS * G)    // 4096
#define WBLOB (K_SZ * NSPAN)          // 15360 floats per (b,s)
#define INV_KP_EXTENT (1.0f / 0.48f)

// ---------- pre-pass: w[b][s][k][n-span 1024] fp32, 60 KB contiguous blob ----
__global__ __launch_bounds__(THREADS) void kpconv_weights_s(
    const float* __restrict__ p, const float* __restrict__ kp,
    float* __restrict__ wglob) {
  __shared__ float kps[K_SZ * 3];
  const int tid = threadIdx.x;
  if (tid < K_SZ * 3) kps[tid] = kp[tid];
  __syncthreads();

  const size_t g = (size_t)blockIdx.x * THREADS + tid;  // over B*N
  const int b  = (int)(g / N_SZ);
  const int n  = (int)(g % N_SZ);
  const int s  = n / NSPAN;
  const int nn = n % NSPAN;
  const float px = p[g * 3 + 0], py = p[g * 3 + 1], pz = p[g * 3 + 2];
  float* wout = wglob + (size_t)(b * S_SPANS + s) * WBLOB + nn;
#pragma unroll
  for (int k = 0; k < K_SZ; ++k) {
    const float dx = px - kps[3 * k + 0];
    const float dy = py - kps[3 * k + 1];
    const float dz = pz - kps[3 * k + 2];
    const float d = sqrtf(fmaf(dx, dx, fmaf(dy, dy, dz * dz)));
    wout[k * NSPAN] = fmaxf(1.0f - d * INV_KP_EXTENT, 0.0f);
  }
}

// ---------- main: stage w->LDS ONCE, then barrier-free x streaming -----------
__global__ __launch_bounds__(THREADS, 2) void kpconv_main_sb(
    const float* __restrict__ x, const float* __restrict__ wglob,
    float* __restrict__ part) {
  __shared__ float wlds[WBLOB];   // 60 KB

  const int tid = threadIdx.x;
  const int blk = blockIdx.x;     // (b*S_SPANS + s)*G + cg
  const int cg = blk % G;
  const int bs = blk / G;
  const int b  = bs / S_SPANS;
  const int s  = bs % S_SPANS;
  const int lane = tid & 63;
  const int wid  = tid >> 6;

  // stage the 60 KB w blob (contiguous) into LDS
  {
    const float4* src = reinterpret_cast<const float4*>(wglob + (size_t)bs * WBLOB);
    float4* dst = reinterpret_cast<float4*>(wlds);
#pragma unroll
    for (int j = 0; j < WBLOB / 4 / THREADS; ++j)   // 15 iters
      dst[tid + THREADS * j] = src[tid + THREADS * j];
  }

  const float* xl = x + (size_t)b * C_SZ * N_SZ
                  + (size_t)(cg * C_BLK + wid * ROWS) * N_SZ
                  + s * NSPAN + NPL * lane;

  float acc[ROWS][K_SZ];
#pragma unroll
  for (int r = 0; r < ROWS; ++r)
#pragma unroll
    for (int k = 0; k < K_SZ; ++k) acc[r][k] = 0.0f;

#define LOADX(dst, t)                                                         \
  do {                                                                        \
    _Pragma("unroll")                                                         \
    for (int r_ = 0; r_ < ROWS; ++r_)                                         \
      dst[r_] = *reinterpret_cast<const float2*>(                             \
          xl + (size_t)r_ * N_SZ + (t) * WSTEP);                              \
  } while (0)

#define DOFMA(xv, t)                                                          \
  do {                                                                        \
    _Pragma("unroll")                                                         \
    for (int k_ = 0; k_ < K_SZ; ++k_) {                                       \
      const float2 w2_ = *reinterpret_cast<const float2*>(                    \
          &wlds[k_ * NSPAN + (t) * WSTEP + NPL * lane]);                      \
      _Pragma("unroll")                                                       \
      for (int r_ = 0; r_ < ROWS; ++r_)                                       \
        acc[r_][k_] = fmaf(w2_.y, xv[r_].y,                                   \
                      fmaf(w2_.x, xv[r_].x, acc[r_][k_]));                    \
    }                                                                         \
  } while (0)

  float2 xA[ROWS], xB[ROWS];
  LOADX(xA, 0);          // overlaps the stage drain
  __syncthreads();       // the ONLY barrier: wlds ready

  for (int t = 0; t < STEPS; t += 2) {
    LOADX(xB, t + 1);
    DOFMA(xA, t);
    if (t + 2 < STEPS) LOADX(xA, t + 2);
    DOFMA(xB, t + 1);
  }

  // reduce acc[r][k] across 64 lanes (n); lane k keeps k; lanes 0..14 store.
  float* pout = part + (size_t)blk * PART_PER_BLK + wid * (ROWS * K_SZ);
#pragma unroll
  for (int r = 0; r < ROWS; ++r) {
    float keep = 0.0f;
#pragma unroll
    for (int k = 0; k < K_SZ; ++k) {
      float v = acc[r][k];
      v += __shfl_xor(v, 1);
      v += __shfl_xor(v, 2);
      v += __shfl_xor(v, 4);
      v += __shfl_xor(v, 8);
      v += __shfl_xor(v, 16);
      v += __shfl_xor(v, 32);
      if (lane == k) keep = v;
    }
    if (lane < K_SZ) pout[r * K_SZ + lane] = keep;
  }
}

// ---------- fallback (ws too small): inline weight compute, same part layout --
__global__ __launch_bounds__(THREADS, 2) void kpconv_main_fb2(
    const float* __restrict__ p, const float* __restrict__ x,
    const float* __restrict__ kp, float* __restrict__ part) {
  __shared__ float kps[K_SZ * 3];
  const int tid = threadIdx.x;
  if (tid < K_SZ * 3) kps[tid] = kp[tid];
  __syncthreads();

  const int blk = blockIdx.x;
  const int cg = blk % G;
  const int bs = blk / G;
  const int b  = bs / S_SPANS;
  const int s  = bs % S_SPANS;
  const int lane = tid & 63;
  const int wid  = tid >> 6;

  const float* xl = x + (size_t)b * C_SZ * N_SZ
                  + (size_t)(cg * C_BLK + wid * ROWS) * N_SZ
                  + s * NSPAN + NPL * lane;
  const float* pb = p + ((size_t)b * N_SZ + s * NSPAN) * 3;

  float acc[ROWS][K_SZ];
#pragma unroll
  for (int r = 0; r < ROWS; ++r)
#pragma unroll
    for (int k = 0; k < K_SZ; ++k) acc[r][k] = 0.0f;

  for (int t = 0; t < STEPS; ++t) {
    float2 xv[ROWS];
    LOADX(xv, t);
    const int n0 = t * WSTEP + NPL * lane;
    const float px0 = pb[3 * n0 + 0], py0 = pb[3 * n0 + 1], pz0 = pb[3 * n0 + 2];
    const float px1 = pb[3 * n0 + 3], py1 = pb[3 * n0 + 4], pz1 = pb[3 * n0 + 5];
#pragma unroll
    for (int k = 0; k < K_SZ; ++k) {
      const float kx = kps[3 * k + 0], ky = kps[3 * k + 1], kz = kps[3 * k + 2];
      const float dx0 = px0 - kx, dy0 = py0 - ky, dz0 = pz0 - kz;
      const float dx1 = px1 - kx, dy1 = py1 - ky, dz1 = pz1 - kz;
      const float w0 = fmaxf(1.0f - sqrtf(fmaf(dx0, dx0, fmaf(dy0, dy0, dz0 * dz0))) * INV_KP_EXTENT, 0.0f);
      const float w1 = fmaxf(1.0f - sqrtf(fmaf(dx1, dx1, fmaf(dy1, dy1, dz1 * dz1))) * INV_KP_EXTENT, 0.0f);
#pragma unroll
      for (int r = 0; r < ROWS; ++r)
        acc[r][k] = fmaf(w1, xv[r].y, fmaf(w0, xv[r].x, acc[r][k]));
    }
  }

  float* pout = part + (size_t)blk * PART_PER_BLK + wid * (ROWS * K_SZ);
#pragma unroll
  for (int r = 0; r < ROWS; ++r) {
    float keep = 0.0f;
#pragma unroll
    for (int k = 0; k < K_SZ; ++k) {
      float v = acc[r][k];
      v += __shfl_xor(v, 1);
      v += __shfl_xor(v, 2);
      v += __shfl_xor(v, 4);
      v += __shfl_xor(v, 8);
      v += __shfl_xor(v, 16);
      v += __shfl_xor(v, 32);
      if (lane == k) keep = v;
    }
    if (lane < K_SZ) pout[r * K_SZ + lane] = keep;
  }
}

// part[(b*S_SPANS+s)*G + cg][wid][r][k];  c = cg*16 + wid*4 + r.
__global__ __launch_bounds__(C_SZ) void kpconv_reduce_gemm(
    const float* __restrict__ part, const float* __restrict__ W,
    float* __restrict__ out) {
  const int k = blockIdx.x;    // 0..14
  const int b = blockIdx.y;    // 0..7
  const int tid = threadIdx.x; // c
  __shared__ float row[C_SZ];

  const int cg = tid >> 4, wid = (tid >> 2) & 3, r = tid & 3;
  const size_t base = ((size_t)(b * S_SPANS) * G + cg) * PART_PER_BLK
                    + wid * (ROWS * K_SZ) + r * K_SZ + k;
  float sum = 0.0f;
  for (int ss = 0; ss < S_SPANS; ++ss)
    sum += part[base + (size_t)ss * G * PART_PER_BLK];
  row[tid] = sum;
  __syncthreads();

  float acc = 0.0f;
  const float* Wk = W + (size_t)k * C_SZ * C_SZ;
#pragma unroll 8
  for (int c = 0; c < C_SZ; ++c) acc += row[c] * Wk[(size_t)c * C_SZ + tid];
  atomicAdd(&out[b * C_SZ + tid], acc);
}

extern "C" void kernel_launch(void* const* d_in, const int* in_sizes, int n_in,
                              void* d_out, int out_size, void* d_ws, size_t ws_size,
                              hipStream_t stream) {
  const float* p  = (const float*)d_in[0];
  const float* x  = (const float*)d_in[1];
  const float* w  = (const float*)d_in[2];
  const float* kp = (const float*)d_in[3];
  float* out  = (float*)d_out;
  float* part = (float*)d_ws;

  const size_t part_bytes = (size_t)NBLKS * PART_PER_BLK * sizeof(float);   // 3.93 MB
  const size_t walign = (part_bytes + 255) & ~(size_t)255;
  const size_t wbytes = (size_t)B_SZ * S_SPANS * WBLOB * sizeof(float);     // 31.5 MB

  (void)hipMemsetAsync(d_out, 0, (size_t)out_size * sizeof(float), stream);
  if (ws_size >= walign + wbytes) {
    float* wglob = (float*)((char*)d_ws + walign);
    kpconv_weights_s<<<dim3(B_SZ * N_SZ / THREADS), THREADS, 0, stream>>>(p, kp, wglob);
    kpconv_main_sb<<<dim3(NBLKS), THREADS, 0, stream>>>(x, wglob, part);
  } else {
    kpconv_main_fb2<<<dim3(NBLKS), THREADS, 0, stream>>>(p, x, kp, part);
  }
  kpconv_reduce_gemm<<<dim3(K_SZ, B_SZ), C_SZ, 0, stream>>>(part, w, out);
}

// Round 12
// 105.924 us; speedup vs baseline: 7.0569x; 7.0569x over previous
//
#include <hip/hip_runtime.h>
#include <hip/hip_fp16.h>

#define B_SZ 8
#define N_SZ 65536
#define C_SZ 128
#define K_SZ 15
#define KROWS 16                      // allocated k rows in wglob (15 used)
#define THREADS 256
#define ROWS 4                        // c-rows per wave
#define C_BLK 16                      // c-rows per block (4 waves x 4)
#define G 8                           // c-groups (C_SZ / C_BLK)
#define NPL 4                         // n per lane per step
#define WSTEP 256                     // 64 lanes * NPL
#define NSPAN 2048                    // n-span per block
#define S_SPANS 32                    // N_SZ / NSPAN
#define STEPS 8                       // NSPAN / WSTEP
#define PART_PER_BLK (C_BLK * K_SZ)   // 240
#define NBLKS (B_SZ * S_SPANS * G)    // 2048
#define INV_KP_EXTENT (1.0f / 0.48f)

struct alignas(8) h4 { __half2 a, b; };   // 4 consecutive fp16 (8 B)

// ---------- pre-pass: wglob[b][k][n] fp16 (k-major; per-k wave writes 128 B) --
__global__ __launch_bounds__(THREADS) void kpconv_weights_h(
    const float* __restrict__ p, const float* __restrict__ kp,
    __half* __restrict__ wglob) {
  __shared__ float kps[K_SZ * 3];
  const int tid = threadIdx.x;
  if (tid < K_SZ * 3) kps[tid] = kp[tid];
  __syncthreads();

  const size_t g = (size_t)blockIdx.x * THREADS + tid;   // over B*N
  const int b = (int)(g / N_SZ);
  const int n = (int)(g % N_SZ);
  const float px = p[g * 3 + 0], py = p[g * 3 + 1], pz = p[g * 3 + 2];
  __half* wout = wglob + (size_t)b * (KROWS * N_SZ) + n;
#pragma unroll
  for (int k = 0; k < K_SZ; ++k) {
    const float dx = px - kps[3 * k + 0];
    const float dy = py - kps[3 * k + 1];
    const float dz = pz - kps[3 * k + 2];
    const float d = sqrtf(fmaf(dx, dx, fmaf(dy, dy, dz * dz)));
    wout[(size_t)k * N_SZ] = __float2half(fmaxf(1.0f - d * INV_KP_EXTENT, 0.0f));
  }
}

// ---------- main: barrier-free, LDS-free; w fp16 direct reads (L1-broadcast) --
__global__ __launch_bounds__(THREADS, 2) void kpconv_main_h(
    const float* __restrict__ x, const __half* __restrict__ wglob,
    float* __restrict__ part) {
  const int tid = threadIdx.x;
  const int blk = blockIdx.x;     // (b*S_SPANS + s)*G + cg
  const int cg = blk % G;
  const int bs = blk / G;
  const int b  = bs / S_SPANS;
  const int s  = bs % S_SPANS;
  const int lane = tid & 63;
  const int wid  = tid >> 6;

  const float* xl = x + (size_t)b * C_SZ * N_SZ
                  + (size_t)(cg * C_BLK + wid * ROWS) * N_SZ
                  + s * NSPAN + NPL * lane;
  const h4* wl = reinterpret_cast<const h4*>(
                     wglob + (size_t)b * (KROWS * N_SZ) + s * NSPAN) + lane;
  // w index for (k, t): wl[k*(N_SZ/4) + t*(WSTEP/4)]

  float acc[ROWS][K_SZ];
#pragma unroll
  for (int r = 0; r < ROWS; ++r)
#pragma unroll
    for (int k = 0; k < K_SZ; ++k) acc[r][k] = 0.0f;

#define LOADX(dst, t)                                                         \
  do {                                                                        \
    _Pragma("unroll")                                                         \
    for (int r_ = 0; r_ < ROWS; ++r_)                                         \
      dst[r_] = *reinterpret_cast<const float4*>(                             \
          xl + (size_t)r_ * N_SZ + (t) * WSTEP);                              \
  } while (0)

// k processed in 5 groups of 3 to bound transient w registers (6 VGPR)
#define FMASTEP(xv, t)                                                        \
  do {                                                                        \
    _Pragma("unroll")                                                         \
    for (int kg_ = 0; kg_ < 5; ++kg_) {                                       \
      h4 wr_[3];                                                              \
      _Pragma("unroll")                                                       \
      for (int j_ = 0; j_ < 3; ++j_)                                          \
        wr_[j_] = wl[(size_t)(kg_ * 3 + j_) * (N_SZ / 4) + (t) * (WSTEP / 4)];\
      _Pragma("unroll")                                                       \
      for (int j_ = 0; j_ < 3; ++j_) {                                        \
        const int k_ = kg_ * 3 + j_;                                          \
        const float2 f0_ = __half22float2(wr_[j_].a);                         \
        const float2 f1_ = __half22float2(wr_[j_].b);                         \
        _Pragma("unroll")                                                     \
        for (int r_ = 0; r_ < ROWS; ++r_)                                     \
          acc[r_][k_] = fmaf(f0_.x, xv[r_].x,                                 \
                        fmaf(f0_.y, xv[r_].y,                                 \
                        fmaf(f1_.x, xv[r_].z,                                 \
                        fmaf(f1_.y, xv[r_].w, acc[r_][k_]))));                \
      }                                                                       \
    }                                                                         \
  } while (0)

  float4 xA[ROWS], xB[ROWS];
  LOADX(xA, 0);

  for (int t = 0; t < STEPS; t += 2) {
    LOADX(xB, t + 1);
    FMASTEP(xA, t);
    if (t + 2 < STEPS) LOADX(xA, t + 2);
    FMASTEP(xB, t + 1);
  }

  // reduce acc[r][k] across 64 lanes (n); lane k keeps k; lanes 0..14 store.
  float* pout = part + (size_t)blk * PART_PER_BLK + wid * (ROWS * K_SZ);
#pragma unroll
  for (int r = 0; r < ROWS; ++r) {
    float keep = 0.0f;
#pragma unroll
    for (int k = 0; k < K_SZ; ++k) {
      float v = acc[r][k];
      v += __shfl_xor(v, 1);
      v += __shfl_xor(v, 2);
      v += __shfl_xor(v, 4);
      v += __shfl_xor(v, 8);
      v += __shfl_xor(v, 16);
      v += __shfl_xor(v, 32);
      if (lane == k) keep = v;
    }
    if (lane < K_SZ) pout[r * K_SZ + lane] = keep;
  }
}

// ---------- fallback (ws too small): inline weight compute ------------------
__global__ __launch_bounds__(THREADS, 2) void kpconv_main_fb(
    const float* __restrict__ p, const float* __restrict__ x,
    const float* __restrict__ kp, float* __restrict__ part) {
  __shared__ float kps[K_SZ * 3];
  const int tid = threadIdx.x;
  if (tid < K_SZ * 3) kps[tid] = kp[tid];
  __syncthreads();

  const int blk = blockIdx.x;
  const int cg = blk % G;
  const int bs = blk / G;
  const int b  = bs / S_SPANS;
  const int s  = bs % S_SPANS;
  const int lane = tid & 63;
  const int wid  = tid >> 6;

  const float* xl = x + (size_t)b * C_SZ * N_SZ
                  + (size_t)(cg * C_BLK + wid * ROWS) * N_SZ
                  + s * NSPAN + NPL * lane;
  const float* pb = p + ((size_t)b * N_SZ + s * NSPAN) * 3;

  float acc[ROWS][K_SZ];
#pragma unroll
  for (int r = 0; r < ROWS; ++r)
#pragma unroll
    for (int k = 0; k < K_SZ; ++k) acc[r][k] = 0.0f;

  for (int t = 0; t < STEPS; ++t) {
    float4 xv[ROWS];
    LOADX(xv, t);
    const int n0 = t * WSTEP + NPL * lane;
    float w4[4][K_SZ];
#pragma unroll
    for (int j = 0; j < 4; ++j) {
      const float px = pb[3 * (n0 + j) + 0];
      const float py = pb[3 * (n0 + j) + 1];
      const float pz = pb[3 * (n0 + j) + 2];
#pragma unroll
      for (int k = 0; k < K_SZ; ++k) {
        const float dx = px - kps[3 * k + 0];
        const float dy = py - kps[3 * k + 1];
        const float dz = pz - kps[3 * k + 2];
        const float d = sqrtf(fmaf(dx, dx, fmaf(dy, dy, dz * dz)));
        w4[j][k] = fmaxf(1.0f - d * INV_KP_EXTENT, 0.0f);
      }
    }
#pragma unroll
    for (int k = 0; k < K_SZ; ++k)
#pragma unroll
      for (int r = 0; r < ROWS; ++r)
        acc[r][k] = fmaf(w4[0][k], xv[r].x,
                    fmaf(w4[1][k], xv[r].y,
                    fmaf(w4[2][k], xv[r].z,
                    fmaf(w4[3][k], xv[r].w, acc[r][k]))));
  }

  float* pout = part + (size_t)blk * PART_PER_BLK + wid * (ROWS * K_SZ);
#pragma unroll
  for (int r = 0; r < ROWS; ++r) {
    float keep = 0.0f;
#pragma unroll
    for (int k = 0; k < K_SZ; ++k) {
      float v = acc[r][k];
      v += __shfl_xor(v, 1);
      v += __shfl_xor(v, 2);
      v += __shfl_xor(v, 4);
      v += __shfl_xor(v, 8);
      v += __shfl_xor(v, 16);
      v += __shfl_xor(v, 32);
      if (lane == k) keep = v;
    }
    if (lane < K_SZ) pout[r * K_SZ + lane] = keep;
  }
}

// part[(b*S_SPANS+s)*G + cg][wid][r][k];  c = cg*16 + wid*4 + r.
__global__ __launch_bounds__(C_SZ) void kpconv_reduce_gemm(
    const float* __restrict__ part, const float* __restrict__ W,
    float* __restrict__ out) {
  const int k = blockIdx.x;    // 0..14
  const int b = blockIdx.y;    // 0..7
  const int tid = threadIdx.x; // c
  __shared__ float row[C_SZ];

  const int cg = tid >> 4, wid = (tid >> 2) & 3, r = tid & 3;
  const size_t base = ((size_t)(b * S_SPANS) * G + cg) * PART_PER_BLK
                    + wid * (ROWS * K_SZ) + r * K_SZ + k;
  float sum = 0.0f;
  for (int ss = 0; ss < S_SPANS; ++ss)
    sum += part[base + (size_t)ss * G * PART_PER_BLK];
  row[tid] = sum;
  __syncthreads();

  float acc = 0.0f;
  const float* Wk = W + (size_t)k * C_SZ * C_SZ;
#pragma unroll 8
  for (int c = 0; c < C_SZ; ++c) acc += row[c] * Wk[(size_t)c * C_SZ + tid];
  atomicAdd(&out[b * C_SZ + tid], acc);
}

extern "C" void kernel_launch(void* const* d_in, const int* in_sizes, int n_in,
                              void* d_out, int out_size, void* d_ws, size_t ws_size,
                              hipStream_t stream) {
  const float* p  = (const float*)d_in[0];
  const float* x  = (const float*)d_in[1];
  const float* w  = (const float*)d_in[2];
  const float* kp = (const float*)d_in[3];
  float* out  = (float*)d_out;
  float* part = (float*)d_ws;

  const size_t part_bytes = (size_t)NBLKS * PART_PER_BLK * sizeof(float);   // 1.97 MB
  const size_t walign = (part_bytes + 255) & ~(size_t)255;
  const size_t wbytes = (size_t)B_SZ * KROWS * N_SZ * sizeof(__half);       // 16.78 MB

  (void)hipMemsetAsync(d_out, 0, (size_t)out_size * sizeof(float), stream);
  if (ws_size >= walign + wbytes) {
    __half* wglob = (__half*)((char*)d_ws + walign);
    kpconv_weights_h<<<dim3(B_SZ * N_SZ / THREADS), THREADS, 0, stream>>>(p, kp, wglob);
    kpconv_main_h<<<dim3(NBLKS), THREADS, 0, stream>>>(x, wglob, part);
  } else {
    kpconv_main_fb<<<dim3(NBLKS), THREADS, 0, stream>>>(p, x, kp, part);
  }
  kpconv_reduce_gemm<<<dim3(K_SZ, B_SZ), C_SZ, 0, stream>>>(part, w, out);
}

// Round 14
// 102.015 us; speedup vs baseline: 7.3273x; 1.0383x over previous
//
#include <hip/hip_runtime.h>
#include <hip/hip_fp16.h>

#define B_SZ 8
#define N_SZ 65536
#define C_SZ 128
#define K_SZ 15
#define KROWS 16                      // k rows in wglob (row 15 = zero pad)
#define THREADS 256
#define S_SPANS 128                   // n-spans per batch
#define NSPAN 512                     // n per block
#define WAVE_N 128                    // n per wave
#define MSTEPS (WAVE_N / 32)          // 4 mfma steps per wave
#define NBLKS (B_SZ * S_SPANS)        // 1024
#define TILE_F (KROWS * C_SZ)         // 2048 floats per block partial
#define INV_KP_EXTENT (1.0f / 0.48f)

typedef _Float16 half8_t __attribute__((ext_vector_type(8)));
typedef __fp16 fp16x2_t __attribute__((ext_vector_type(2)));
typedef float float4_t __attribute__((ext_vector_type(4)));

// ---------- pre-pass: wglob[b][k][n] fp16, k-major -----------------------------
__global__ __launch_bounds__(THREADS) void kpconv_weights_h(
    const float* __restrict__ p, const float* __restrict__ kp,
    __half* __restrict__ wglob) {
  __shared__ float kps[K_SZ * 3];
  __shared__ float pl[THREADS * 3];
  const int tid = threadIdx.x;
  if (tid < K_SZ * 3) kps[tid] = kp[tid];
  const size_t base = (size_t)blockIdx.x * THREADS;   // point index over B*N
  pl[tid]       = p[base * 3 + tid];
  pl[tid + 256] = p[base * 3 + tid + 256];
  pl[tid + 512] = p[base * 3 + tid + 512];
  __syncthreads();
  const int b = (int)(base / N_SZ);
  const int n = (int)(base % N_SZ) + tid;
  const float px = pl[3 * tid], py = pl[3 * tid + 1], pz = pl[3 * tid + 2];
  __half* wout = wglob + (size_t)b * (KROWS * N_SZ) + n;
#pragma unroll
  for (int k = 0; k < K_SZ; ++k) {
    const float dx = px - kps[3 * k + 0];
    const float dy = py - kps[3 * k + 1];
    const float dz = pz - kps[3 * k + 2];
    const float d = sqrtf(fmaf(dx, dx, fmaf(dy, dy, dz * dz)));
    wout[(size_t)k * N_SZ] = __float2half(fmaxf(1.0f - d * INV_KP_EXTENT, 0.0f));
  }
  wout[(size_t)15 * N_SZ] = __float2half(0.0f);
}

// ---------- main: MFMA GEMM wf[k][c] = sum_n w[k][n] * x[c][n] ----------------
// A-frag: lane(16q+r) holds w[r][n0+8q .. +8] (8 fp16, one 16B load).
// B-frag: lane(16q+r) holds x[c=r+16*ct][n0+8q .. +8] (8 fp32 -> cvt_pkrtz).
// D: lane(16q+r) reg j = wf[k=4q+j][c=16*ct+r]  (verified C/D layout).
__global__ __launch_bounds__(THREADS, 2) void kpconv_mfma(
    const float* __restrict__ x, const __half* __restrict__ wglob,
    float* __restrict__ part) {
  __shared__ float red[4 * TILE_F];   // 32 KB

  const int tid = threadIdx.x;
  const int bs = blockIdx.x;          // b * S_SPANS + s
  const int b = bs / S_SPANS;
  const int s = bs % S_SPANS;
  const int lane = tid & 63;
  const int wid = tid >> 6;
  const int q = lane >> 4;
  const int r = lane & 15;

  const int n0 = s * NSPAN + wid * WAVE_N + q * 8;
  const __half* wl = wglob + (size_t)b * (KROWS * N_SZ) + (size_t)r * N_SZ + n0;
  const float*  xl = x + (size_t)b * (C_SZ * N_SZ) + (size_t)r * N_SZ + n0;

  float4_t acc[8];
#pragma unroll
  for (int ct = 0; ct < 8; ++ct)
#pragma unroll
    for (int j = 0; j < 4; ++j) acc[ct][j] = 0.0f;

#pragma unroll 2
  for (int t = 0; t < MSTEPS; ++t) {
    const half8_t a = *reinterpret_cast<const half8_t*>(wl + t * 32);
#pragma unroll
    for (int ct = 0; ct < 8; ++ct) {
      const float* xp = xl + (size_t)ct * 16 * N_SZ + t * 32;
      const float4_t x0 = *reinterpret_cast<const float4_t*>(xp);
      const float4_t x1 = *reinterpret_cast<const float4_t*>(xp + 4);
      union { half8_t v; fp16x2_t h[4]; } bb;
      bb.h[0] = __builtin_amdgcn_cvt_pkrtz(x0[0], x0[1]);
      bb.h[1] = __builtin_amdgcn_cvt_pkrtz(x0[2], x0[3]);
      bb.h[2] = __builtin_amdgcn_cvt_pkrtz(x1[0], x1[1]);
      bb.h[3] = __builtin_amdgcn_cvt_pkrtz(x1[2], x1[3]);
      acc[ct] = __builtin_amdgcn_mfma_f32_16x16x32_f16(a, bb.v, acc[ct], 0, 0, 0);
    }
  }

  // stash wave partial into LDS, then 4-way cross-wave reduce -> part[bs][2048]
#pragma unroll
  for (int ct = 0; ct < 8; ++ct)
#pragma unroll
    for (int j = 0; j < 4; ++j)
      red[wid * TILE_F + (q * 4 + j) * C_SZ + ct * 16 + r] = acc[ct][j];
  __syncthreads();

  float* pp = part + (size_t)bs * TILE_F;
  for (int i = tid; i < TILE_F; i += THREADS)
    pp[i] = red[i] + red[TILE_F + i] + red[2 * TILE_F + i] + red[3 * TILE_F + i];
}

// ---------- reduce over spans + per-k GEMM into out ---------------------------
__global__ __launch_bounds__(C_SZ) void kpconv_reduce_mf(
    const float* __restrict__ part, const float* __restrict__ W,
    float* __restrict__ out) {
  const int k = blockIdx.x;    // 0..14 (pad row 15 never read)
  const int b = blockIdx.y;    // 0..7
  const int tid = threadIdx.x; // c / co
  __shared__ float row[C_SZ];

  float sum = 0.0f;
  const float* pp = part + (size_t)b * S_SPANS * TILE_F + k * C_SZ + tid;
  for (int s = 0; s < S_SPANS; ++s) sum += pp[(size_t)s * TILE_F];
  row[tid] = sum;
  __syncthreads();

  float acc = 0.0f;
  const float* Wk = W + (size_t)k * C_SZ * C_SZ;
#pragma unroll 8
  for (int c = 0; c < C_SZ; ++c) acc = fmaf(row[c], Wk[(size_t)c * C_SZ + tid], acc);
  atomicAdd(&out[b * C_SZ + tid], acc);
}

// ---------- fallback (ws too small): round-12 proven VALU path ----------------
#define FB_ROWS 4
#define FB_G 8
#define FB_NPL 4
#define FB_WSTEP 256
#define FB_NSPAN 2048
#define FB_SPANS 32
#define FB_STEPS 8
#define FB_PART (16 * K_SZ)           // 240
#define FB_NBLKS (B_SZ * FB_SPANS * FB_G)

__global__ __launch_bounds__(THREADS, 2) void kpconv_main_fb(
    const float* __restrict__ p, const float* __restrict__ x,
    const float* __restrict__ kp, float* __restrict__ part) {
  __shared__ float kps[K_SZ * 3];
  const int tid = threadIdx.x;
  if (tid < K_SZ * 3) kps[tid] = kp[tid];
  __syncthreads();

  const int blk = blockIdx.x;
  const int cg = blk % FB_G;
  const int bs = blk / FB_G;
  const int b  = bs / FB_SPANS;
  const int s  = bs % FB_SPANS;
  const int lane = tid & 63;
  const int wid  = tid >> 6;

  const float* xl = x + (size_t)b * C_SZ * N_SZ
                  + (size_t)(cg * 16 + wid * FB_ROWS) * N_SZ
                  + s * FB_NSPAN + FB_NPL * lane;
  const float* pb = p + ((size_t)b * N_SZ + s * FB_NSPAN) * 3;

  float acc[FB_ROWS][K_SZ];
#pragma unroll
  for (int r = 0; r < FB_ROWS; ++r)
#pragma unroll
    for (int k = 0; k < K_SZ; ++k) acc[r][k] = 0.0f;

  for (int t = 0; t < FB_STEPS; ++t) {
    float4 xv[FB_ROWS];
#pragma unroll
    for (int r = 0; r < FB_ROWS; ++r)
      xv[r] = *reinterpret_cast<const float4*>(xl + (size_t)r * N_SZ + t * FB_WSTEP);
    const int n0 = t * FB_WSTEP + FB_NPL * lane;
    float w4[4][K_SZ];
#pragma unroll
    for (int j = 0; j < 4; ++j) {
      const float px = pb[3 * (n0 + j) + 0];
      const float py = pb[3 * (n0 + j) + 1];
      const float pz = pb[3 * (n0 + j) + 2];
#pragma unroll
      for (int k = 0; k < K_SZ; ++k) {
        const float dx = px - kps[3 * k + 0];
        const float dy = py - kps[3 * k + 1];
        const float dz = pz - kps[3 * k + 2];
        const float d = sqrtf(fmaf(dx, dx, fmaf(dy, dy, dz * dz)));
        w4[j][k] = fmaxf(1.0f - d * INV_KP_EXTENT, 0.0f);
      }
    }
#pragma unroll
    for (int k = 0; k < K_SZ; ++k)
#pragma unroll
      for (int r = 0; r < FB_ROWS; ++r)
        acc[r][k] = fmaf(w4[0][k], xv[r].x,
                    fmaf(w4[1][k], xv[r].y,
                    fmaf(w4[2][k], xv[r].z,
                    fmaf(w4[3][k], xv[r].w, acc[r][k]))));
  }

  float* pout = part + (size_t)blk * FB_PART + wid * (FB_ROWS * K_SZ);
#pragma unroll
  for (int r = 0; r < FB_ROWS; ++r) {
    float keep = 0.0f;
#pragma unroll
    for (int k = 0; k < K_SZ; ++k) {
      float v = acc[r][k];
      v += __shfl_xor(v, 1);
      v += __shfl_xor(v, 2);
      v += __shfl_xor(v, 4);
      v += __shfl_xor(v, 8);
      v += __shfl_xor(v, 16);
      v += __shfl_xor(v, 32);
      if (lane == k) keep = v;
    }
    if (lane < K_SZ) pout[r * K_SZ + lane] = keep;
  }
}

__global__ __launch_bounds__(C_SZ) void kpconv_reduce_fb(
    const float* __restrict__ part, const float* __restrict__ W,
    float* __restrict__ out) {
  const int k = blockIdx.x;
  const int b = blockIdx.y;
  const int tid = threadIdx.x;
  __shared__ float row[C_SZ];

  const int cg = tid >> 4, wid = (tid >> 2) & 3, r = tid & 3;
  const size_t base = ((size_t)(b * FB_SPANS) * FB_G + cg) * FB_PART
                    + wid * (FB_ROWS * K_SZ) + r * K_SZ + k;
  float sum = 0.0f;
  for (int ss = 0; ss < FB_SPANS; ++ss)
    sum += part[base + (size_t)ss * FB_G * FB_PART];
  row[tid] = sum;
  __syncthreads();

  float acc = 0.0f;
  const float* Wk = W + (size_t)k * C_SZ * C_SZ;
#pragma unroll 8
  for (int c = 0; c < C_SZ; ++c) acc += row[c] * Wk[(size_t)c * C_SZ + tid];
  atomicAdd(&out[b * C_SZ + tid], acc);
}

extern "C" void kernel_launch(void* const* d_in, const int* in_sizes, int n_in,
                              void* d_out, int out_size, void* d_ws, size_t ws_size,
                              hipStream_t stream) {
  const float* p  = (const float*)d_in[0];
  const float* x  = (const float*)d_in[1];
  const float* w  = (const float*)d_in[2];
  const float* kp = (const float*)d_in[3];
  float* out  = (float*)d_out;
  float* part = (float*)d_ws;

  const size_t part_bytes = (size_t)NBLKS * TILE_F * sizeof(float);       // 8.39 MB
  const size_t walign = (part_bytes + 255) & ~(size_t)255;
  const size_t wbytes = (size_t)B_SZ * KROWS * N_SZ * sizeof(__half);     // 16.78 MB

  (void)hipMemsetAsync(d_out, 0, (size_t)out_size * sizeof(float), stream);
  if (ws_size >= walign + wbytes) {
    __half* wglob = (__half*)((char*)d_ws + walign);
    kpconv_weights_h<<<dim3(B_SZ * N_SZ / THREADS), THREADS, 0, stream>>>(p, kp, wglob);
    kpconv_mfma<<<dim3(NBLKS), THREADS, 0, stream>>>(x, wglob, part);
    kpconv_reduce_mf<<<dim3(K_SZ, B_SZ), C_SZ, 0, stream>>>(part, w, out);
  } else {
    kpconv_main_fb<<<dim3(FB_NBLKS), THREADS, 0, stream>>>(p, x, kp, part);
    kpconv_reduce_fb<<<dim3(K_SZ, B_SZ), C_SZ, 0, stream>>>(part, w, out);
  }
}